// Round 9
// baseline (232.655 us; speedup 1.0000x reference)
//
#include <hip/hip_runtime.h>
#include <hip/hip_bf16.h>
#include <stdint.h>

#define OUTF 4096
#define INF  4096
#define MROWS 4096
#define GS 32

typedef __attribute__((ext_vector_type(8))) __bf16 bf16x8;
typedef __attribute__((ext_vector_type(4))) float f32x4;

__device__ inline void gload_lds16(const void* g, void* l) {
    __builtin_amdgcn_global_load_lds(
        (const __attribute__((address_space(1))) void*)g,
        (__attribute__((address_space(3))) void*)l, 16, 0, 0);
}

// Gather the 12 packed bytes of group `gid` (harness stores int8 input as
// sign-extended int32, 4B per packed byte).
__device__ inline void load_group_bits(const int* __restrict__ wq, int gid,
                                       uint64_t& lo, uint64_t& hi) {
    const int4* p = (const int4*)(wq + (size_t)gid * 12);
    int4 A = p[0], B = p[1], C = p[2];
    uint32_t d0 = (uint32_t)(A.x & 255) | ((uint32_t)(A.y & 255) << 8) |
                  ((uint32_t)(A.z & 255) << 16) | ((uint32_t)(A.w & 255) << 24);
    uint32_t d1 = (uint32_t)(B.x & 255) | ((uint32_t)(B.y & 255) << 8) |
                  ((uint32_t)(B.z & 255) << 16) | ((uint32_t)(B.w & 255) << 24);
    uint32_t d2 = (uint32_t)(C.x & 255) | ((uint32_t)(C.y & 255) << 8) |
                  ((uint32_t)(C.z & 255) << 16) | ((uint32_t)(C.w & 255) << 24);
    lo = (uint64_t)d0 | ((uint64_t)d1 << 32);
    hi = (uint64_t)d1 | ((uint64_t)d2 << 32);
}

// ---------------- fused prepass: x->bf16 (blocks 0..8191), W dequant (rest) --
__global__ void prep_kernel(const float* __restrict__ x, __bf16* __restrict__ xb,
                            const int* __restrict__ wq, const float* __restrict__ wn,
                            __bf16* __restrict__ wb) {
    const int bid = blockIdx.x;
    if (bid < 8192) {
        int i = bid * 256 + threadIdx.x;  // 2M threads, 8 floats each
        const f32x4* xp = (const f32x4*)x;
        f32x4 a = xp[2 * i], b = xp[2 * i + 1];
        bf16x8 v = { (__bf16)a[0], (__bf16)a[1], (__bf16)a[2], (__bf16)a[3],
                     (__bf16)b[0], (__bf16)b[1], (__bf16)b[2], (__bf16)b[3] };
        ((bf16x8*)xb)[i] = v;
    } else {
        int gid = (bid - 8192) * 256 + threadIdx.x;  // one 32-elem group
        uint64_t lo, hi;
        load_group_bits(wq, gid, lo, hi);
        float nrm = wn[gid];
        float c2 = nrm * (2.0f / 7.0f), c1 = -nrm;  // w = q*(2n/7) - n
        bf16x8 o[4];
#pragma unroll
        for (int j = 0; j < 32; ++j) {
            uint32_t q = (j <= 20) ? (uint32_t)((lo >> (3 * j)) & 7)
                                   : (uint32_t)((hi >> (3 * j - 32)) & 7);
            o[j >> 3][j & 7] = (__bf16)((float)q * c2 + c1);
        }
        bf16x8* outp = (bf16x8*)(wb + (size_t)gid * 32);
        outp[0] = o[0]; outp[1] = o[1]; outp[2] = o[2]; outp[3] = o[3];
    }
}

// ========== 256x256 GEMM: A direct global->reg, B via LDS (dbuf) ==========
// 512 thr = 8 waves (4M x 2N); per-wave 64 rows x 128 cols (acc[4][8] f32x4).
// A: per wave per K-tile 8 x global_load_dwordx4 (16-row x 64B pattern,
//    L1/L2-served; A-panel LLC-resident, reuse x2 in-CU) -> NO barrier dep.
// B: LDS 2 x 32KB [256 rows][64 bf16] (128B rows), chunk^=row&7 swizzle
//    (conflict-free, verified R3-R7), gload_lds staged 1 tile ahead.
// One barrier + one trailing vmcnt(0) per K-tile (stage landed long ago;
// A-loads already consumed) -> waves skew, LDS/VMEM overlap MFMA cross-wave.

#define VMCNT0() asm volatile("s_waitcnt vmcnt(0)" ::: "memory")
#define BARR() do { asm volatile("" ::: "memory"); __builtin_amdgcn_s_barrier(); \
                    asm volatile("" ::: "memory"); } while (0)

__global__ __launch_bounds__(512, 2) void gemmA_kernel(
    const __bf16* __restrict__ xb, const __bf16* __restrict__ wb,
    const float* __restrict__ bias, float* __restrict__ out) {
    __shared__ __align__(16) unsigned char lds[2 * 32768];

    const int tid = threadIdx.x;
    const int lane = tid & 63, wid = tid >> 6;
    const int wr = wid >> 1, wc = wid & 1;
    const int row16 = lane & 15, kq = lane >> 4;

    // XCD-aware swizzle (256 wgs, bijective)
    const int bid = blockIdx.x;
    const int wg = (bid & 7) * 32 + (bid >> 3);
    const int bn = wg & 15, bm = wg >> 4;

    // B staging geometry: linear LDS dest, pre-swizzled global source chunk
    const int srow = tid >> 3;
    const int schunk = (tid & 7) ^ (srow & 7);
    const __bf16* pb = wb + (size_t)(bn * 256 + srow) * INF + schunk * 8;

    // A direct-load base: lane (row16,kq) reads row ...+row16, col kq*8
    const __bf16* pa = xb + (size_t)(bm * 256 + wr * 64 + row16) * INF + kq * 8;

    f32x4 acc[4][8] = {};
    bf16x8 a[4][2];

    // B read offsets (row R = wc*128 + n*16 + row16, chunk (kk*4+kq)^(R&7))
    int boff[8][2];
#pragma unroll
    for (int n = 0; n < 8; ++n) {
        const int R = wc * 128 + n * 16 + row16;
#pragma unroll
        for (int kk = 0; kk < 2; ++kk)
            boff[n][kk] = R * 128 + (((kk * 4 + kq) * 16) ^ ((R & 7) << 4));
    }

    // prologue: stage B tile 0 into buf0
#pragma unroll
    for (int j = 0; j < 4; ++j)
        gload_lds16(pb + (size_t)j * 64 * INF, lds + j * 8192 + tid * 16);
    VMCNT0();
    BARR();

    for (int kt = 0; kt < INF / 64; ++kt) {
        const int rb = kt & 1, sb = rb ^ 1;
        // stage B(kt+1) early (latency hidden under this tile's compute)
        if (kt < INF / 64 - 1) {
#pragma unroll
            for (int j = 0; j < 4; ++j)
                gload_lds16(pb + (size_t)j * 64 * INF + (kt + 1) * 64,
                            lds + sb * 32768 + j * 8192 + tid * 16);
        }
        // A fragments for this tile: 8 vmem b128, register dataflow only
#pragma unroll
        for (int m = 0; m < 4; ++m)
#pragma unroll
            for (int kk = 0; kk < 2; ++kk)
                a[m][kk] = *(const bf16x8*)(pa + (size_t)m * 16 * INF + kt * 64 + kk * 32);
        // B from LDS per n-block, MFMA
#pragma unroll
        for (int n = 0; n < 8; ++n) {
            bf16x8 b0 = *(const bf16x8*)(lds + rb * 32768 + boff[n][0]);
            bf16x8 b1 = *(const bf16x8*)(lds + rb * 32768 + boff[n][1]);
            __builtin_amdgcn_s_setprio(1);
#pragma unroll
            for (int m = 0; m < 4; ++m) {
                acc[m][n] = __builtin_amdgcn_mfma_f32_16x16x32_bf16(a[m][0], b0, acc[m][n], 0, 0, 0);
                acc[m][n] = __builtin_amdgcn_mfma_f32_16x16x32_bf16(a[m][1], b1, acc[m][n], 0, 0, 0);
            }
            __builtin_amdgcn_s_setprio(0);
        }
        VMCNT0();   // stage(kt+1) issued ~1 tile ago: lands free; A consumed
        BARR();     // safe to read sb next tile / overwrite rb next stage
    }

    // epilogue: C = acc + bias (16x16 C layout: col=lane&15, row=kq*4+j)
#pragma unroll
    for (int n = 0; n < 8; ++n) {
        const int col = bn * 256 + wc * 128 + n * 16 + row16;
        const float bv = bias[col];
#pragma unroll
        for (int m = 0; m < 4; ++m) {
            const int rbase = bm * 256 + wr * 64 + m * 16 + kq * 4;
#pragma unroll
            for (int j = 0; j < 4; ++j)
                out[(size_t)(rbase + j) * OUTF + col] = acc[m][n][j] + bv;
        }
    }
}

// ---------------- fallback (no workspace): fused 128^2 kernel ----------------
__global__ __launch_bounds__(256, 2) void gemm_fb_kernel(
    const float* __restrict__ x, const int* __restrict__ wq,
    const float* __restrict__ wn, const float* __restrict__ bias,
    float* __restrict__ out) {
    __shared__ __align__(16) unsigned char lAraw[128 * 128];
    __shared__ __align__(16) unsigned char lBraw[128 * 128];

    const int tid = threadIdx.x;
    const int lane = tid & 63, wid = tid >> 6;
    const int wr = wid >> 1, wc = wid & 1;
    const int bn = blockIdx.x, bm = blockIdx.y;
    const int row16 = lane & 15, kq = lane >> 4;

    f32x4 acc[4][4] = {};

    int aoff[4], boff[4];
#pragma unroll
    for (int m = 0; m < 4; ++m) {
        int r = wr * 64 + m * 16 + row16;
        aoff[m] = r * 128 + ((kq * 16) ^ ((r & 7) << 4));
    }
#pragma unroll
    for (int n = 0; n < 4; ++n) {
        int r = wc * 64 + n * 16 + row16;
        boff[n] = r * 128 + ((kq * 16) ^ ((r & 7) << 4));
    }

    for (int kt = 0; kt < INF / 64; ++kt) {
        __syncthreads();
#pragma unroll
        for (int it = 0; it < 4; ++it) {
            int row = it * 32 + (tid >> 3), c = tid & 7;
            const f32x4* xp = (const f32x4*)(x + (size_t)(bm * 128 + row) * INF + kt * 64 + c * 8);
            f32x4 a0 = xp[0], a1 = xp[1];
            bf16x8 v = { (__bf16)a0[0], (__bf16)a0[1], (__bf16)a0[2], (__bf16)a0[3],
                         (__bf16)a1[0], (__bf16)a1[1], (__bf16)a1[2], (__bf16)a1[3] };
            *(bf16x8*)(lAraw + row * 128 + ((c * 16) ^ ((row & 7) << 4))) = v;
        }
        {
            int row = tid >> 1, gi = tid & 1;
            int gid = (bn * 128 + row) * (INF / GS) + kt * 2 + gi;
            uint64_t lo, hi;
            load_group_bits(wq, gid, lo, hi);
            float nrm = wn[gid];
            float c2 = nrm * (2.0f / 7.0f), c1 = -nrm;
            bf16x8 o[4];
#pragma unroll
            for (int j = 0; j < 32; ++j) {
                uint32_t q = (j <= 20) ? (uint32_t)((lo >> (3 * j)) & 7)
                                       : (uint32_t)((hi >> (3 * j - 32)) & 7);
                o[j >> 3][j & 7] = (__bf16)((float)q * c2 + c1);
            }
            unsigned swz = (row & 7) << 4;
#pragma unroll
            for (int c4 = 0; c4 < 4; ++c4)
                *(bf16x8*)(lBraw + row * 128 + ((gi * 64 + c4 * 16) ^ swz)) = o[c4];
        }
        __syncthreads();

#pragma unroll
        for (int kk = 0; kk < 2; ++kk) {
            bf16x8 afr[4], bfr[4];
#pragma unroll
            for (int m = 0; m < 4; ++m)
                afr[m] = *(const bf16x8*)(lAraw + (aoff[m] ^ (kk * 64)));
#pragma unroll
            for (int n = 0; n < 4; ++n)
                bfr[n] = *(const bf16x8*)(lBraw + (boff[n] ^ (kk * 64)));
#pragma unroll
            for (int m = 0; m < 4; ++m)
#pragma unroll
                for (int n = 0; n < 4; ++n)
                    acc[m][n] = __builtin_amdgcn_mfma_f32_16x16x32_bf16(afr[m], bfr[n], acc[m][n], 0, 0, 0);
        }
    }

#pragma unroll
    for (int n = 0; n < 4; ++n) {
        int col = bn * 128 + wc * 64 + n * 16 + row16;
        float bv = bias[col];
#pragma unroll
        for (int m = 0; m < 4; ++m) {
            int rbase = bm * 128 + wr * 64 + m * 16 + kq * 4;
#pragma unroll
            for (int j = 0; j < 4; ++j)
                out[(size_t)(rbase + j) * OUTF + col] = acc[m][n][j] + bv;
        }
    }
}

extern "C" void kernel_launch(void* const* d_in, const int* in_sizes, int n_in,
                              void* d_out, int out_size, void* d_ws, size_t ws_size,
                              hipStream_t stream) {
    const float* x    = (const float*)d_in[0];
    const int*   wq   = (const int*)d_in[1];
    const float* wn   = (const float*)d_in[2];
    const float* bias = (const float*)d_in[3];
    float* out = (float*)d_out;

    const size_t xb_bytes = (size_t)MROWS * INF * 2;  // 32 MB
    const size_t wb_bytes = (size_t)OUTF * INF * 2;   // 32 MB
    if (ws_size >= xb_bytes + wb_bytes) {
        __bf16* xb = (__bf16*)d_ws;
        __bf16* wb = (__bf16*)((char*)d_ws + xb_bytes);
        prep_kernel<<<8192 + (OUTF * INF / GS) / 256, 256, 0, stream>>>(x, xb, wq, wn, wb);
        gemmA_kernel<<<(MROWS / 256) * (OUTF / 256), 512, 0, stream>>>(xb, wb, bias, out);
    } else {
        gemm_fb_kernel<<<dim3(OUTF / 128, MROWS / 128), 256, 0, stream>>>(x, wq, wn, bias, out);
    }
}